// Round 1
// baseline (3572.684 us; speedup 1.0000x reference)
//
#include <hip/hip_runtime.h>
#include <hip/hip_bf16.h>

#define N_ATOMS 10000
#define N_EDGES 320000
#define H 256
#define H3 768
#define N_RBF 20
#define LN_EPS 1e-5f

__device__ __forceinline__ float silu_f(float x) { return x / (1.f + __expf(-x)); }

// ---------------- LayerNorm: one block (256 thr) per atom ----------------
__global__ __launch_bounds__(256) void k_ln(const float* __restrict__ s,
                                            const float* __restrict__ g,
                                            const float* __restrict__ b,
                                            float* __restrict__ sn) {
    int a = blockIdx.x, t = threadIdx.x;
    float x = s[(size_t)a * H + t];
    __shared__ float red[4];
    float v = x;
    for (int o = 32; o > 0; o >>= 1) v += __shfl_down(v, o);
    if ((t & 63) == 0) red[t >> 6] = v;
    __syncthreads();
    float mu = (red[0] + red[1] + red[2] + red[3]) * (1.f / H);
    float dx = x - mu;
    __syncthreads();
    v = dx * dx;
    for (int o = 32; o > 0; o >>= 1) v += __shfl_down(v, o);
    if ((t & 63) == 0) red[t >> 6] = v;
    __syncthreads();
    float var = (red[0] + red[1] + red[2] + red[3]) * (1.f / H);
    float rs = rsqrtf(var + LN_EPS);
    sn[(size_t)a * H + t] = dx * rs * g[t] + b[t];
}

// ---------------- fp32 tiled GEMM: C = [silu](A@B + bias) ----------------
// A: MxK row-major, B: KxN row-major. BM=BN=64, BK=16, 256 thr, 4x4/thread.
template <int DO_SILU>
__global__ __launch_bounds__(256) void k_gemm(const float* __restrict__ A,
                                              const float* __restrict__ B,
                                              const float* __restrict__ bias,
                                              float* __restrict__ C,
                                              int M, int N, int K) {
    const int BM = 64, BN = 64, BK = 16;
    __shared__ float As[BK][BM + 1];
    __shared__ float Bs[BK][BN + 1];
    int tid = threadIdx.x;
    int m0 = blockIdx.x * BM, n0 = blockIdx.y * BN;
    int ty = tid >> 4, tx = tid & 15;
    float acc[4][4] = {};
    for (int k0 = 0; k0 < K; k0 += BK) {
        {   // A tile 64x16 -> As[k][m]
            int kk = tid & 15, mm = tid >> 4;
            for (int r = 0; r < 4; r++) {
                int m = mm + r * 16;
                int gm = m0 + m;
                As[kk][m] = (gm < M) ? A[(size_t)gm * K + k0 + kk] : 0.f;
            }
        }
        {   // B tile 16x64
            int n = tid & 63, kk = tid >> 6;
            for (int r = 0; r < 4; r++) {
                int k = kk + r * 4;
                Bs[k][n] = B[(size_t)(k0 + k) * N + n0 + n];
            }
        }
        __syncthreads();
        for (int k = 0; k < BK; k++) {
            float a[4], bb[4];
            for (int i = 0; i < 4; i++) a[i] = As[k][ty * 4 + i];
            for (int j = 0; j < 4; j++) bb[j] = Bs[k][tx * 4 + j];
            for (int i = 0; i < 4; i++)
                for (int j = 0; j < 4; j++) acc[i][j] += a[i] * bb[j];
        }
        __syncthreads();
    }
    for (int i = 0; i < 4; i++) {
        int gm = m0 + ty * 4 + i;
        if (gm >= M) continue;
        for (int j = 0; j < 4; j++) {
            int gn = n0 + tx * 4 + j;
            float y = acc[i][j] + bias[gn];
            if (DO_SILU) y = silu_f(y);
            C[(size_t)gm * N + gn] = y;
        }
    }
}

// ---------------- Fused edge kernel ----------------
// Per block: 32 edges x 64 output-cols x 3 segments (ds/dvs/dvv).
// Phase 0: h = silu(rbf @ fw1 + fb1) into LDS (K=20).
// Phase 1: 3-segment GEMM h[32x256] @ fw2-cols, fp32, 4e x 2c per thread.
// Phase 2: epilogue gather ctx[idx_j], v[idx_j]; atomicAdd scatter to outputs.
__global__ __launch_bounds__(256) void k_edge(
    const float* __restrict__ rbf, const float* __restrict__ fw1,
    const float* __restrict__ fb1, const float* __restrict__ fw2,
    const float* __restrict__ fb2, const float* __restrict__ ctx,
    const float* __restrict__ f_cut, const int* __restrict__ idx_i,
    const int* __restrict__ idx_j, const float* __restrict__ dir_ij,
    const float* __restrict__ v_in, const float* __restrict__ inv_ptr,
    float* __restrict__ out_s, float* __restrict__ out_v) {
    const int EB = 32, CB = 64, BK = 16;
    __shared__ float hs[EB][H + 1];
    __shared__ float rbf_s[EB][N_RBF];
    __shared__ float Bs[3][BK][CB + 1];
    int tid = threadIdx.x;
    int e0 = blockIdx.x * EB;
    int c0 = blockIdx.y * CB;

    for (int i = tid; i < EB * N_RBF; i += 256) {
        int e = i / N_RBF, k = i % N_RBF;
        rbf_s[e][k] = rbf[(size_t)(e0 + e) * N_RBF + k];
    }
    __syncthreads();

    {   // h compute: thread owns column `tid` for all 32 edges
        float w1[N_RBF];
        for (int k = 0; k < N_RBF; k++) w1[k] = fw1[k * H + tid];
        float bb = fb1[tid];
        for (int e = 0; e < EB; e++) {
            float acc = bb;
            for (int k = 0; k < N_RBF; k++) acc += rbf_s[e][k] * w1[k];
            hs[e][tid] = silu_f(acc);
        }
    }
    __syncthreads();

    int ty = tid >> 5;   // 0..7  -> edge = ty*4+i
    int tx = tid & 31;   // 0..31 -> col  = tx*2+j
    float acc[3][4][2] = {};
    for (int k0 = 0; k0 < H; k0 += BK) {
        {   // stage fw2 cols for 3 segments
            int n = tid & 63, kk = tid >> 6;
            for (int s = 0; s < 3; s++)
                for (int r = 0; r < 4; r++) {
                    int k = kk + r * 4;
                    Bs[s][k][n] = fw2[(size_t)(k0 + k) * H3 + s * H + c0 + n];
                }
        }
        __syncthreads();
        for (int k = 0; k < BK; k++) {
            float a[4];
            for (int i = 0; i < 4; i++) a[i] = hs[ty * 4 + i][k0 + k];
            float b0[2], b1[2], b2[2];
            for (int j = 0; j < 2; j++) {
                b0[j] = Bs[0][k][tx * 2 + j];
                b1[j] = Bs[1][k][tx * 2 + j];
                b2[j] = Bs[2][k][tx * 2 + j];
            }
            for (int i = 0; i < 4; i++)
                for (int j = 0; j < 2; j++) {
                    acc[0][i][j] += a[i] * b0[j];
                    acc[1][i][j] += a[i] * b1[j];
                    acc[2][i][j] += a[i] * b2[j];
                }
        }
        __syncthreads();
    }

    float inv = inv_ptr[0];
    for (int i = 0; i < 4; i++) {
        int eg = e0 + ty * 4 + i;
        int ii = idx_i[eg], jj = idx_j[eg];
        float fc = f_cut[eg] * inv;
        float d0 = dir_ij[eg * 3 + 0], d1 = dir_ij[eg * 3 + 1], d2 = dir_ij[eg * 3 + 2];
        const float* cj = ctx + (size_t)jj * H3;
        const float* vj = v_in + (size_t)jj * 3 * H;
        float* vo = out_v + (size_t)ii * 3 * H;
        for (int j = 0; j < 2; j++) {
            int c = c0 + tx * 2 + j;
            float wds  = acc[0][i][j] + fb2[c];
            float wdvs = acc[1][i][j] + fb2[H + c];
            float wdvv = acc[2][i][j] + fb2[2 * H + c];
            float ds  = cj[c]         * wds  * fc;
            float dvs = cj[H + c]     * wdvs * fc;
            float dvv = cj[2 * H + c] * wdvv * fc;
            atomicAdd(out_s + (size_t)ii * H + c, ds);
            atomicAdd(vo + 0 * H + c, dvs * d0 + dvv * vj[0 * H + c]);
            atomicAdd(vo + 1 * H + c, dvs * d1 + dvv * vj[1 * H + c]);
            atomicAdd(vo + 2 * H + c, dvs * d2 + dvv * vj[2 * H + c]);
        }
    }
}

extern "C" void kernel_launch(void* const* d_in, const int* in_sizes, int n_in,
                              void* d_out, int out_size, void* d_ws, size_t ws_size,
                              hipStream_t stream) {
    const float* s      = (const float*)d_in[0];
    const float* v      = (const float*)d_in[1];
    const int*   idx_i  = (const int*)d_in[2];
    const int*   idx_j  = (const int*)d_in[3];
    const float* rbf    = (const float*)d_in[4];
    const float* f_cut  = (const float*)d_in[5];
    const float* dir_ij = (const float*)d_in[6];
    const float* inv    = (const float*)d_in[7];
    const float* ln_g   = (const float*)d_in[8];
    const float* ln_b   = (const float*)d_in[9];
    const float* cw1    = (const float*)d_in[10];
    const float* cb1    = (const float*)d_in[11];
    const float* cw2    = (const float*)d_in[12];
    const float* cb2    = (const float*)d_in[13];
    const float* fw1    = (const float*)d_in[14];
    const float* fb1    = (const float*)d_in[15];
    const float* fw2    = (const float*)d_in[16];
    const float* fb2    = (const float*)d_in[17];

    float* out_s = (float*)d_out;
    float* out_v = out_s + (size_t)N_ATOMS * H;

    // ws layout: sn (10.24MB) | ctx1 (10.24MB) | ctx (30.72MB)  = 51.2MB
    float* sn   = (float*)d_ws;
    float* ctx1 = sn + (size_t)N_ATOMS * H;
    float* ctx  = ctx1 + (size_t)N_ATOMS * H;

    // init outputs with s, v (updates are atomically accumulated on top)
    hipMemcpyAsync(out_s, s, sizeof(float) * (size_t)N_ATOMS * H,
                   hipMemcpyDeviceToDevice, stream);
    hipMemcpyAsync(out_v, v, sizeof(float) * (size_t)N_ATOMS * 3 * H,
                   hipMemcpyDeviceToDevice, stream);

    k_ln<<<N_ATOMS, 256, 0, stream>>>(s, ln_g, ln_b, sn);

    dim3 g1((N_ATOMS + 63) / 64, H / 64);
    k_gemm<1><<<g1, 256, 0, stream>>>(sn, cw1, cb1, ctx1, N_ATOMS, H, H);
    dim3 g2((N_ATOMS + 63) / 64, H3 / 64);
    k_gemm<0><<<g2, 256, 0, stream>>>(ctx1, cw2, cb2, ctx, N_ATOMS, H3, H);

    dim3 ge(N_EDGES / 32, H / 64);
    k_edge<<<ge, 256, 0, stream>>>(rbf, fw1, fb1, fw2, fb2, ctx, f_cut,
                                   idx_i, idx_j, dir_ij, v, inv, out_s, out_v);
}

// Round 3
// 1927.311 us; speedup vs baseline: 1.8537x; 1.8537x over previous
//
#include <hip/hip_runtime.h>
#include <hip/hip_bf16.h>

#define N_ATOMS 10000
#define N_EDGES 320000
#define H 256
#define H3 768
#define N_RBF 20
#define LN_EPS 1e-5f

typedef __attribute__((ext_vector_type(8))) short bf16x8;
typedef __attribute__((ext_vector_type(4))) float f32x4;
#define MFMA16 __builtin_amdgcn_mfma_f32_16x16x32_bf16

__device__ __forceinline__ float silu_f(float x) { return x / (1.f + __expf(-x)); }

__device__ __forceinline__ unsigned short f2bf(float x) {
    union { float f; unsigned u; } v; v.f = x;
    unsigned r = v.u + 0x7fff + ((v.u >> 16) & 1);
    return (unsigned short)(r >> 16);
}
__device__ __forceinline__ float bf2f(unsigned short b) {
    union { unsigned u; float f; } v; v.u = ((unsigned)b) << 16; return v.f;
}

// ---------------- LayerNorm: one block (256 thr) per atom ----------------
__global__ __launch_bounds__(256) void k_ln(const float* __restrict__ s,
                                            const float* __restrict__ g,
                                            const float* __restrict__ b,
                                            float* __restrict__ sn) {
    int a = blockIdx.x, t = threadIdx.x;
    float x = s[(size_t)a * H + t];
    __shared__ float red[4];
    float v = x;
    for (int o = 32; o > 0; o >>= 1) v += __shfl_down(v, o);
    if ((t & 63) == 0) red[t >> 6] = v;
    __syncthreads();
    float mu = (red[0] + red[1] + red[2] + red[3]) * (1.f / H);
    float dx = x - mu;
    __syncthreads();
    v = dx * dx;
    for (int o = 32; o > 0; o >>= 1) v += __shfl_down(v, o);
    if ((t & 63) == 0) red[t >> 6] = v;
    __syncthreads();
    float var = (red[0] + red[1] + red[2] + red[3]) * (1.f / H);
    float rs = rsqrtf(var + LN_EPS);
    sn[(size_t)a * H + t] = dx * rs * g[t] + b[t];
}

// ---------------- fp32 tiled GEMM: C = [silu](A@B + bias) ----------------
// A: MxK row-major (fp32 or bf16 per IN_BF16), B: KxN row-major fp32.
template <int DO_SILU, int IN_BF16, int OUT_BF16>
__global__ __launch_bounds__(256) void k_gemm(const void* __restrict__ Av,
                                              const float* __restrict__ B,
                                              const float* __restrict__ bias,
                                              void* __restrict__ Cv,
                                              int M, int N, int K) {
    const int BM = 64, BN = 64, BK = 16;
    __shared__ float As[BK][BM + 1];
    __shared__ float Bs[BK][BN + 1];
    int tid = threadIdx.x;
    int m0 = blockIdx.x * BM, n0 = blockIdx.y * BN;
    int ty = tid >> 4, tx = tid & 15;
    float acc[4][4] = {};
    for (int k0 = 0; k0 < K; k0 += BK) {
        {
            int kk = tid & 15, mm = tid >> 4;
            for (int r = 0; r < 4; r++) {
                int m = mm + r * 16;
                int gm = m0 + m;
                float a = 0.f;
                if (gm < M) {
                    if (IN_BF16) a = bf2f(((const unsigned short*)Av)[(size_t)gm * K + k0 + kk]);
                    else         a = ((const float*)Av)[(size_t)gm * K + k0 + kk];
                }
                As[kk][m] = a;
            }
        }
        {
            int n = tid & 63, kk = tid >> 6;
            for (int r = 0; r < 4; r++) {
                int k = kk + r * 4;
                Bs[k][n] = B[(size_t)(k0 + k) * N + n0 + n];
            }
        }
        __syncthreads();
        for (int k = 0; k < BK; k++) {
            float a[4], bb[4];
            for (int i = 0; i < 4; i++) a[i] = As[k][ty * 4 + i];
            for (int j = 0; j < 4; j++) bb[j] = Bs[k][tx * 4 + j];
            for (int i = 0; i < 4; i++)
                for (int j = 0; j < 4; j++) acc[i][j] += a[i] * bb[j];
        }
        __syncthreads();
    }
    for (int i = 0; i < 4; i++) {
        int gm = m0 + ty * 4 + i;
        if (gm >= M) continue;
        for (int j = 0; j < 4; j++) {
            int gn = n0 + tx * 4 + j;
            float y = acc[i][j] + bias[gn];
            if (DO_SILU) y = silu_f(y);
            if (OUT_BF16) ((unsigned short*)Cv)[(size_t)gm * N + gn] = f2bf(y);
            else          ((float*)Cv)[(size_t)gm * N + gn] = y;
        }
    }
}

// ---------------- weight prep: fw2 -> transposed split hi/lo bf16 ----------
// fw2t2[n][0..255] = hi(fw2[:,n]), fw2t2[n][256..511] = lo.
__global__ __launch_bounds__(256) void k_prep_fw2t2(const float* __restrict__ fw2,
                                                    unsigned short* __restrict__ fw2t2) {
    int n = blockIdx.x, k = threadIdx.x;           // n<768, k<256
    float wv = fw2[(size_t)k * H3 + n];
    unsigned short hi = f2bf(wv);
    unsigned short lo = f2bf(wv - bf2f(hi));
    fw2t2[(size_t)n * 512 + k] = hi;
    fw2t2[(size_t)n * 512 + 256 + k] = lo;
}

// ---------------- counting sort by idx_i ----------------
__global__ __launch_bounds__(256) void k_hist(const int* __restrict__ idx_i,
                                              int* __restrict__ counts) {
    int e = blockIdx.x * 256 + threadIdx.x;
    if (e < N_EDGES) atomicAdd(&counts[idx_i[e]], 1);
}
__global__ __launch_bounds__(256) void k_scan(const int* __restrict__ counts,
                                              int* __restrict__ rowstart) {
    __shared__ int part[257];
    int t = threadIdx.x;
    const int PER = 40;
    int s = 0;
    for (int r = 0; r < PER; ++r) { int i = t * PER + r; if (i < N_ATOMS) s += counts[i]; }
    part[t + 1] = s;
    if (t == 0) part[0] = 0;
    __syncthreads();
    for (int off = 1; off < 256; off <<= 1) {
        int v = (t + 1 > off) ? part[t + 1 - off] : 0;
        __syncthreads();
        part[t + 1] += v;
        __syncthreads();
    }
    int run = part[t];
    for (int r = 0; r < PER; ++r) {
        int i = t * PER + r;
        if (i < N_ATOMS) { rowstart[i] = run; run += counts[i]; }
    }
    if (t == 255) rowstart[N_ATOMS] = run;
}
__global__ __launch_bounds__(256) void k_scatter(const int* __restrict__ idx_i,
                                                 const int* __restrict__ rowstart,
                                                 int* __restrict__ cursor,
                                                 int* __restrict__ perm) {
    int e = blockIdx.x * 256 + threadIdx.x;
    if (e >= N_EDGES) return;
    int i = idx_i[e];
    int p = rowstart[i] + atomicAdd(&cursor[i], 1);
    perm[p] = e;
}
__global__ __launch_bounds__(256) void k_gather(const int* __restrict__ perm,
                                                const int* __restrict__ idx_i,
                                                const int* __restrict__ idx_j,
                                                const float* __restrict__ f_cut,
                                                const float* __restrict__ dir_ij,
                                                const float* __restrict__ inv_ptr,
                                                int* __restrict__ si, int* __restrict__ sj,
                                                float* __restrict__ sfc,
                                                float* __restrict__ sdir) {
    int p = blockIdx.x * 256 + threadIdx.x;
    if (p >= N_EDGES) return;
    int e = perm[p];
    si[p] = idx_i[e];
    sj[p] = idx_j[e];
    sfc[p] = f_cut[e] * inv_ptr[0];
    sdir[p * 3 + 0] = dir_ij[e * 3 + 0];
    sdir[p * 3 + 1] = dir_ij[e * 3 + 1];
    sdir[p * 3 + 2] = dir_ij[e * 3 + 2];
}

// ---------------- fused edge kernel (split-bf16 MFMA, fp32-grade) ----------
// Block: 128 sorted edges x col-tile ct (64 cols x 3 segs). 8 K-chunks of 32.
// h computed fp32 on VALU from rbf (staged via perm), split hi/lo bf16 in LDS.
// W GEMM: 3 MFMA passes (whi*hhi + whi*hlo + wlo*hhi) -> ~fp32 accuracy.
__global__ __launch_bounds__(256, 2) void k_edge(
    const int* __restrict__ perm, const float* __restrict__ rbf,
    const int* __restrict__ si, const int* __restrict__ sj,
    const float* __restrict__ sfc, const float* __restrict__ sdir,
    const float* __restrict__ fw1, const float* __restrict__ fb1,
    const unsigned short* __restrict__ fw2t2, const float* __restrict__ fb2,
    const float* __restrict__ ctx, const float* __restrict__ v_in,
    float* __restrict__ out_s, float* __restrict__ out_v) {
    __shared__ char sm[53248];
    float* s_rbf = (float*)sm;        // [128][24] f32, 12KB
    char* s_h2 = sm + 12288;          // [128][128B] bf16: hi k0..31 | lo k0..31
    char* s_w2 = sm + 28672;          // [192][128B] bf16: hi 32k | lo 32k

    int tid = threadIdx.x;
    int lane = tid & 63, w = tid >> 6;
    int l16 = lane & 15, g4 = lane >> 4;
    int e0 = blockIdx.x * 128;
    int ct = blockIdx.y;

    {   // stage rbf rows (fp32) via perm; row = 96B, 5 float4 used
        int e_l = tid & 127, half = tid >> 7;
        int e = perm[e0 + e_l];
        const float4* src = (const float4*)(rbf + (size_t)e * N_RBF);
        float4* dst = (float4*)(s_rbf + e_l * 24);
        if (half == 0) { dst[0] = src[0]; dst[1] = src[1]; dst[2] = src[2]; }
        else           { dst[3] = src[3]; dst[4] = src[4]; }
    }
    __syncthreads();

    f32x4 acc[12][2];
#pragma unroll
    for (int a = 0; a < 12; a++)
#pragma unroll
        for (int b = 0; b < 2; b++) acc[a][b] = (f32x4){0.f, 0.f, 0.f, 0.f};

    int c_l = tid & 31, g = tid >> 5;   // col-in-chunk, edge-group (16 edges)

    for (int q = 0; q < 8; ++q) {
        // (a) prefetch weight tile (hi+lo): 6 x dwordx4 / thread
        uint4 wreg[6];
#pragma unroll
        for (int r = 0; r < 6; ++r) {
            int u = tid + 256 * r;                 // 1536 = 192 rows x 8 slots
            int n = u >> 3, sl = u & 7;
            int n_glob = (n >> 6) * 256 + ct * 64 + (n & 63);
            int koff = (sl < 4) ? (q * 32 + sl * 8) : (256 + q * 32 + (sl - 4) * 8);
            wreg[r] = *(const uint4*)(fw2t2 + (size_t)n_glob * 512 + koff);
        }
        // (b) h chunk in fp32 VALU, split-store to LDS
        {
            int cg = q * 32 + c_l;
            float w1[N_RBF];
#pragma unroll
            for (int k = 0; k < N_RBF; k++) w1[k] = fw1[k * H + cg];
            float b1 = fb1[cg];
#pragma unroll
            for (int i = 0; i < 16; ++i) {
                int e_l = g * 16 + i;
                float x = b1;
#pragma unroll
                for (int k = 0; k < N_RBF; k++) x += s_rbf[e_l * 24 + k] * w1[k];
                float h = silu_f(x);
                unsigned short hi = f2bf(h);
                unsigned short lo = f2bf(h - bf2f(hi));
                char* base = s_h2 + e_l * 128;
                int swz = (e_l & 7) << 4;
                *(unsigned short*)(base + ((2 * c_l) ^ swz)) = hi;
                *(unsigned short*)(base + ((64 + 2 * c_l) ^ swz)) = lo;
            }
        }
        // (c) write weight tile to LDS (WAR barrier first)
        __syncthreads();
#pragma unroll
        for (int r = 0; r < 6; ++r) {
            int u = tid + 256 * r;
            int n = u >> 3, sl = u & 7;
            *(uint4*)(s_w2 + n * 128 + ((sl * 16) ^ ((n & 7) << 4))) = wreg[r];
        }
        __syncthreads();
        // (d) MFMA: 3 split combos over this 32-K chunk
        bf16x8 bh_hi[2], bh_lo[2];
#pragma unroll
        for (int ef = 0; ef < 2; ef++) {
            int e = 32 * w + 16 * ef + l16;
            int swz = (e & 7) << 4;
            bh_hi[ef] = *(const bf16x8*)(s_h2 + e * 128 + ((16 * g4) ^ swz));
            bh_lo[ef] = *(const bf16x8*)(s_h2 + e * 128 + ((64 + 16 * g4) ^ swz));
        }
#pragma unroll
        for (int nf = 0; nf < 12; nf++) {
            int n = nf * 16 + l16;
            int swzn = (n & 7) << 4;
            bf16x8 aw_hi = *(const bf16x8*)(s_w2 + n * 128 + ((16 * g4) ^ swzn));
            bf16x8 aw_lo = *(const bf16x8*)(s_w2 + n * 128 + ((64 + 16 * g4) ^ swzn));
#pragma unroll
            for (int ef = 0; ef < 2; ef++) {
                acc[nf][ef] = MFMA16(aw_hi, bh_hi[ef], acc[nf][ef], 0, 0, 0);
                acc[nf][ef] = MFMA16(aw_hi, bh_lo[ef], acc[nf][ef], 0, 0, 0);
                acc[nf][ef] = MFMA16(aw_lo, bh_hi[ef], acc[nf][ef], 0, 0, 0);
            }
        }
    }

    // ---------------- epilogue ----------------
#pragma unroll
    for (int ef = 0; ef < 2; ++ef) {
        int E = e0 + 32 * w + 16 * ef + l16;
        int ai = si[E], aj = sj[E];
        float fc = sfc[E];
        float d0 = sdir[3 * E], d1 = sdir[3 * E + 1], d2 = sdir[3 * E + 2];
        int i1 = __shfl_down(ai, 1, 16), i2 = __shfl_down(ai, 2, 16);
        int i4 = __shfl_down(ai, 4, 16), i8 = __shfl_down(ai, 8, 16);
        int prevai = __shfl_up(ai, 1, 16);
        bool m1 = (l16 + 1 < 16) && (i1 == ai);
        bool m2 = (l16 + 2 < 16) && (i2 == ai);
        bool m4 = (l16 + 4 < 16) && (i4 == ai);
        bool m8 = (l16 + 8 < 16) && (i8 == ai);
        bool lead = (l16 == 0) || (prevai != ai);
        const float* cj = ctx + (size_t)aj * H3;
        const float* vj = v_in + (size_t)aj * H3;
#pragma unroll
        for (int ci = 0; ci < 4; ++ci) {
            float vds[4], vv0[4], vv1[4], vv2[4];
#pragma unroll
            for (int r = 0; r < 4; ++r) {
                int C = ct * 64 + ci * 16 + g4 * 4 + r;
                float w0 = acc[ci][ef][r]     + fb2[C];
                float w1 = acc[4 + ci][ef][r] + fb2[H + C];
                float w2 = acc[8 + ci][ef][r] + fb2[2 * H + C];
                float ds  = cj[C]         * w0 * fc;
                float dvs = cj[H + C]     * w1 * fc;
                float dvv = cj[2 * H + C] * w2 * fc;
                vds[r] = ds;
                vv0[r] = dvs * d0 + dvv * vj[C];
                vv1[r] = dvs * d1 + dvv * vj[H + C];
                vv2[r] = dvs * d2 + dvv * vj[2 * H + C];
            }
            // segmented Hillis-Steele suffix scan within 16-lane window
#pragma unroll
            for (int st = 0; st < 4; ++st) {
                int off = 1 << st;
                bool m = (st == 0) ? m1 : (st == 1) ? m2 : (st == 2) ? m4 : m8;
#pragma unroll
                for (int r = 0; r < 4; ++r) {
                    float t0 = __shfl_down(vds[r], off, 16);
                    float t1 = __shfl_down(vv0[r], off, 16);
                    float t2 = __shfl_down(vv1[r], off, 16);
                    float t3 = __shfl_down(vv2[r], off, 16);
                    if (m) { vds[r] += t0; vv0[r] += t1; vv1[r] += t2; vv2[r] += t3; }
                }
            }
            if (lead) {
#pragma unroll
                for (int r = 0; r < 4; ++r) {
                    int C = ct * 64 + ci * 16 + g4 * 4 + r;
                    atomicAdd(&out_s[(size_t)ai * H + C], vds[r]);
                    atomicAdd(&out_v[(size_t)ai * H3 + C], vv0[r]);
                    atomicAdd(&out_v[(size_t)ai * H3 + H + C], vv1[r]);
                    atomicAdd(&out_v[(size_t)ai * H3 + 2 * H + C], vv2[r]);
                }
            }
        }
    }
}

extern "C" void kernel_launch(void* const* d_in, const int* in_sizes, int n_in,
                              void* d_out, int out_size, void* d_ws, size_t ws_size,
                              hipStream_t stream) {
    const float* s      = (const float*)d_in[0];
    const float* v      = (const float*)d_in[1];
    const int*   idx_i  = (const int*)d_in[2];
    const int*   idx_j  = (const int*)d_in[3];
    const float* rbf    = (const float*)d_in[4];
    const float* f_cut  = (const float*)d_in[5];
    const float* dir_ij = (const float*)d_in[6];
    const float* inv    = (const float*)d_in[7];
    const float* ln_g   = (const float*)d_in[8];
    const float* ln_b   = (const float*)d_in[9];
    const float* cw1    = (const float*)d_in[10];
    const float* cb1    = (const float*)d_in[11];
    const float* cw2    = (const float*)d_in[12];
    const float* cb2    = (const float*)d_in[13];
    const float* fw1    = (const float*)d_in[14];
    const float* fb1    = (const float*)d_in[15];
    const float* fw2    = (const float*)d_in[16];
    const float* fb2    = (const float*)d_in[17];

    float* out_s = (float*)d_out;
    float* out_v = out_s + (size_t)N_ATOMS * H;

    // ---- ws layout (bytes), peak 46,989,312 (< 51.2MB proven in round 1) ----
    char* wsb = (char*)d_ws;
    unsigned short* fw2t2    = (unsigned short*)(wsb + 0);          //    786,432
    int*            counts   = (int*)(wsb + 786432);                //     40,960
    int*            rowstart = (int*)(wsb + 827392);                //     40,960
    int*            cursor   = (int*)(wsb + 868352);                //     40,960
    float*          ctx      = (float*)(wsb + 909312);              // 30,720,000 (fp32)
    float*          sn       = (float*)(wsb + 31629312);            // 10,240,000 (dead after gemm1)
    unsigned short* ctx1     = (unsigned short*)(wsb + 41869312);   //  5,120,000 bf16
    // overlays of sn region (written only after gemm1 consumed sn):
    int*            perm     = (int*)(wsb + 31629312);              //  1,280,000
    int*            si       = (int*)(wsb + 32909312);
    int*            sj       = (int*)(wsb + 34189312);
    float*          sfc      = (float*)(wsb + 35469312);
    float*          sdir     = (float*)(wsb + 36749312);            //  3,840,000

    // init outputs with s, v (updates accumulated atomically on top)
    hipMemcpyAsync(out_s, s, sizeof(float) * (size_t)N_ATOMS * H,
                   hipMemcpyDeviceToDevice, stream);
    hipMemcpyAsync(out_v, v, sizeof(float) * (size_t)N_ATOMS * 3 * H,
                   hipMemcpyDeviceToDevice, stream);
    hipMemsetAsync(counts, 0, 122880, stream);   // counts+rowstart+cursor

    // weight prep + histogram (low region only)
    k_prep_fw2t2<<<768, 256, 0, stream>>>(fw2, fw2t2);
    k_hist<<<(N_EDGES + 255) / 256, 256, 0, stream>>>(idx_i, counts);
    k_scan<<<1, 256, 0, stream>>>(counts, rowstart);

    // context path (uses sn, then ctx1, then ctx)
    k_ln<<<N_ATOMS, 256, 0, stream>>>(s, ln_g, ln_b, sn);
    dim3 g1((N_ATOMS + 63) / 64, H / 64);
    k_gemm<1, 0, 1><<<g1, 256, 0, stream>>>(sn, cw1, cb1, ctx1, N_ATOMS, H, H);

    // sort outputs overlay sn (dead now)
    k_scatter<<<(N_EDGES + 255) / 256, 256, 0, stream>>>(idx_i, rowstart, cursor, perm);
    k_gather<<<(N_EDGES + 255) / 256, 256, 0, stream>>>(
        perm, idx_i, idx_j, f_cut, dir_ij, inv, si, sj, sfc, sdir);

    dim3 g2((N_ATOMS + 63) / 64, H3 / 64);
    k_gemm<0, 1, 0><<<g2, 256, 0, stream>>>(ctx1, cw2, cb2, ctx, N_ATOMS, H3, H);

    // fused edge GEMM + scatter
    dim3 ge(N_EDGES / 128, 4);
    k_edge<<<ge, 256, 0, stream>>>(perm, rbf, si, sj, sfc, sdir, fw1, fb1,
                                   fw2t2, fb2, ctx, v, out_s, out_v);
}

// Round 4
// 1540.211 us; speedup vs baseline: 2.3196x; 1.2513x over previous
//
#include <hip/hip_runtime.h>
#include <hip/hip_bf16.h>

#define N_ATOMS 10000
#define N_EDGES 320000
#define H 256
#define H3 768
#define N_RBF 20
#define LN_EPS 1e-5f

typedef __attribute__((ext_vector_type(8))) short bf16x8;
typedef __attribute__((ext_vector_type(4))) float f32x4;
#define MFMA16 __builtin_amdgcn_mfma_f32_16x16x32_bf16

__device__ __forceinline__ float silu_f(float x) { return x / (1.f + __expf(-x)); }

__device__ __forceinline__ unsigned short f2bf(float x) {
    union { float f; unsigned u; } v; v.f = x;
    unsigned r = v.u + 0x7fff + ((v.u >> 16) & 1);
    return (unsigned short)(r >> 16);
}
__device__ __forceinline__ float bf2f(unsigned short b) {
    union { unsigned u; float f; } v; v.u = ((unsigned)b) << 16; return v.f;
}

// ---------------- LayerNorm: one block (256 thr) per atom ----------------
__global__ __launch_bounds__(256) void k_ln(const float* __restrict__ s,
                                            const float* __restrict__ g,
                                            const float* __restrict__ b,
                                            float* __restrict__ sn) {
    int a = blockIdx.x, t = threadIdx.x;
    float x = s[(size_t)a * H + t];
    __shared__ float red[4];
    float v = x;
    for (int o = 32; o > 0; o >>= 1) v += __shfl_down(v, o);
    if ((t & 63) == 0) red[t >> 6] = v;
    __syncthreads();
    float mu = (red[0] + red[1] + red[2] + red[3]) * (1.f / H);
    float dx = x - mu;
    __syncthreads();
    v = dx * dx;
    for (int o = 32; o > 0; o >>= 1) v += __shfl_down(v, o);
    if ((t & 63) == 0) red[t >> 6] = v;
    __syncthreads();
    float var = (red[0] + red[1] + red[2] + red[3]) * (1.f / H);
    float rs = rsqrtf(var + LN_EPS);
    sn[(size_t)a * H + t] = dx * rs * g[t] + b[t];
}

// ---------------- fp32 tiled GEMM: C = [silu](A@B + bias) ----------------
template <int DO_SILU, int IN_BF16, int OUT_BF16>
__global__ __launch_bounds__(256) void k_gemm(const void* __restrict__ Av,
                                              const float* __restrict__ B,
                                              const float* __restrict__ bias,
                                              void* __restrict__ Cv,
                                              int M, int N, int K) {
    const int BM = 64, BN = 64, BK = 16;
    __shared__ float As[BK][BM + 1];
    __shared__ float Bs[BK][BN + 1];
    int tid = threadIdx.x;
    int m0 = blockIdx.x * BM, n0 = blockIdx.y * BN;
    int ty = tid >> 4, tx = tid & 15;
    float acc[4][4] = {};
    for (int k0 = 0; k0 < K; k0 += BK) {
        {
            int kk = tid & 15, mm = tid >> 4;
            for (int r = 0; r < 4; r++) {
                int m = mm + r * 16;
                int gm = m0 + m;
                float a = 0.f;
                if (gm < M) {
                    if (IN_BF16) a = bf2f(((const unsigned short*)Av)[(size_t)gm * K + k0 + kk]);
                    else         a = ((const float*)Av)[(size_t)gm * K + k0 + kk];
                }
                As[kk][m] = a;
            }
        }
        {
            int n = tid & 63, kk = tid >> 6;
            for (int r = 0; r < 4; r++) {
                int k = kk + r * 4;
                Bs[k][n] = B[(size_t)(k0 + k) * N + n0 + n];
            }
        }
        __syncthreads();
        for (int k = 0; k < BK; k++) {
            float a[4], bb[4];
            for (int i = 0; i < 4; i++) a[i] = As[k][ty * 4 + i];
            for (int j = 0; j < 4; j++) bb[j] = Bs[k][tx * 4 + j];
            for (int i = 0; i < 4; i++)
                for (int j = 0; j < 4; j++) acc[i][j] += a[i] * bb[j];
        }
        __syncthreads();
    }
    for (int i = 0; i < 4; i++) {
        int gm = m0 + ty * 4 + i;
        if (gm >= M) continue;
        for (int j = 0; j < 4; j++) {
            int gn = n0 + tx * 4 + j;
            float y = acc[i][j] + bias[gn];
            if (DO_SILU) y = silu_f(y);
            if (OUT_BF16) ((unsigned short*)Cv)[(size_t)gm * N + gn] = f2bf(y);
            else          ((float*)Cv)[(size_t)gm * N + gn] = y;
        }
    }
}

// ---------------- weight prep ----------------
// fw2t2[n][0..255]=hi(fw2[:,n]), [256..511]=lo
__global__ __launch_bounds__(256) void k_prep_fw2t2(const float* __restrict__ fw2,
                                                    unsigned short* __restrict__ fw2t2) {
    int n = blockIdx.x, k = threadIdx.x;
    float wv = fw2[(size_t)k * H3 + n];
    unsigned short hi = f2bf(wv);
    unsigned short lo = f2bf(wv - bf2f(hi));
    fw2t2[(size_t)n * 512 + k] = hi;
    fw2t2[(size_t)n * 512 + 256 + k] = lo;
}
// fw1t2[c][0..31]=hi(fw1[k][c]) k-padded, [32..63]=lo
__global__ __launch_bounds__(256) void k_prep_fw1t2(const float* __restrict__ fw1,
                                                    unsigned short* __restrict__ fw1t2) {
    int c = threadIdx.x;
    for (int k = 0; k < 32; k++) {
        float wv = (k < N_RBF) ? fw1[k * H + c] : 0.f;
        unsigned short hi = f2bf(wv);
        unsigned short lo = f2bf(wv - bf2f(hi));
        fw1t2[c * 64 + k] = hi;
        fw1t2[c * 64 + 32 + k] = lo;
    }
}

// ---------------- counting sort by idx_i ----------------
__global__ __launch_bounds__(256) void k_hist(const int* __restrict__ idx_i,
                                              int* __restrict__ counts) {
    int e = blockIdx.x * 256 + threadIdx.x;
    if (e < N_EDGES) atomicAdd(&counts[idx_i[e]], 1);
}
__global__ __launch_bounds__(256) void k_scan(const int* __restrict__ counts,
                                              int* __restrict__ rowstart) {
    __shared__ int part[257];
    int t = threadIdx.x;
    const int PER = 40;
    int s = 0;
    for (int r = 0; r < PER; ++r) { int i = t * PER + r; if (i < N_ATOMS) s += counts[i]; }
    part[t + 1] = s;
    if (t == 0) part[0] = 0;
    __syncthreads();
    for (int off = 1; off < 256; off <<= 1) {
        int v = (t + 1 > off) ? part[t + 1 - off] : 0;
        __syncthreads();
        part[t + 1] += v;
        __syncthreads();
    }
    int run = part[t];
    for (int r = 0; r < PER; ++r) {
        int i = t * PER + r;
        if (i < N_ATOMS) { rowstart[i] = run; run += counts[i]; }
    }
    if (t == 255) rowstart[N_ATOMS] = run;
}
__global__ __launch_bounds__(256) void k_scatter(const int* __restrict__ idx_i,
                                                 const int* __restrict__ rowstart,
                                                 int* __restrict__ cursor,
                                                 int* __restrict__ perm) {
    int e = blockIdx.x * 256 + threadIdx.x;
    if (e >= N_EDGES) return;
    int i = idx_i[e];
    int p = rowstart[i] + atomicAdd(&cursor[i], 1);
    perm[p] = e;
}
__global__ __launch_bounds__(256) void k_gather(const int* __restrict__ perm,
                                                const int* __restrict__ idx_i,
                                                const int* __restrict__ idx_j,
                                                const float* __restrict__ f_cut,
                                                const float* __restrict__ dir_ij,
                                                const float* __restrict__ inv_ptr,
                                                int* __restrict__ si, int* __restrict__ sj,
                                                float* __restrict__ sfc,
                                                float* __restrict__ sdir) {
    int p = blockIdx.x * 256 + threadIdx.x;
    if (p >= N_EDGES) return;
    int e = perm[p];
    si[p] = idx_i[e];
    sj[p] = idx_j[e];
    sfc[p] = f_cut[e] * inv_ptr[0];
    sdir[p * 3 + 0] = dir_ij[e * 3 + 0];
    sdir[p * 3 + 1] = dir_ij[e * 3 + 1];
    sdir[p * 3 + 2] = dir_ij[e * 3 + 2];
}

// ---------------- fused edge kernel (all-MFMA, split-bf16, fp32-grade) ----
// Grid (2500, 8): 128 sorted edges x 96-row col-tile (32 cols x 3 segs).
// h from rbf by split-MFMA (rbf frags in regs, fw1 frags from global);
// s_h2 rows are wave-private (no barrier needed for h store->read).
__global__ __launch_bounds__(256, 3) void k_edge(
    const int* __restrict__ perm, const float* __restrict__ rbf,
    const int* __restrict__ si, const int* __restrict__ sj,
    const float* __restrict__ sfc, const float* __restrict__ sdir,
    const unsigned short* __restrict__ fw1t2, const float* __restrict__ fb1,
    const unsigned short* __restrict__ fw2t2, const float* __restrict__ fb2,
    const float* __restrict__ ctx, const float* __restrict__ v_in,
    float* __restrict__ out_s, float* __restrict__ out_v) {
    __shared__ char sm[28672];
    char* s_h2 = sm;            // [128 e][128B]: hi 32c | lo 32c, swz (e&7)<<4
    char* s_w2 = sm + 16384;    // [96 n][128B]: hi 32k | lo 32k, swz (n&7)<<4

    int tid = threadIdx.x;
    int lane = tid & 63, w = tid >> 6;
    int l16 = lane & 15, g4 = lane >> 4;
    int e0 = blockIdx.x * 128;
    int ct = blockIdx.y;

    // ---- rbf fragments in registers (split bf16), once per block ----
    bf16x8 bfr_hi[2], bfr_lo[2];
#pragma unroll
    for (int ef = 0; ef < 2; ++ef) {
        int e = 32 * w + 16 * ef + l16;
        int pe = perm[e0 + e];
        const float* rr = rbf + (size_t)pe * N_RBF;   // 80B rows, 16B aligned
        float x[8];
#pragma unroll
        for (int t = 0; t < 8; ++t) x[t] = 0.f;
        if (g4 == 0) {
            float4 a = *(const float4*)(rr);
            float4 b = *(const float4*)(rr + 4);
            x[0]=a.x; x[1]=a.y; x[2]=a.z; x[3]=a.w;
            x[4]=b.x; x[5]=b.y; x[6]=b.z; x[7]=b.w;
        } else if (g4 == 1) {
            float4 a = *(const float4*)(rr + 8);
            float4 b = *(const float4*)(rr + 12);
            x[0]=a.x; x[1]=a.y; x[2]=a.z; x[3]=a.w;
            x[4]=b.x; x[5]=b.y; x[6]=b.z; x[7]=b.w;
        } else if (g4 == 2) {
            float4 a = *(const float4*)(rr + 16);     // k 16..19
            x[0]=a.x; x[1]=a.y; x[2]=a.z; x[3]=a.w;
        }
        union { bf16x8 v; unsigned short s[8]; } uh, ul;
#pragma unroll
        for (int t = 0; t < 8; ++t) {
            unsigned short hi = f2bf(x[t]);
            uh.s[t] = hi;
            ul.s[t] = f2bf(x[t] - bf2f(hi));
        }
        bfr_hi[ef] = uh.v;
        bfr_lo[ef] = ul.v;
    }

    f32x4 acc[6][2];
#pragma unroll
    for (int a = 0; a < 6; a++)
#pragma unroll
        for (int b = 0; b < 2; b++) acc[a][b] = (f32x4){0.f, 0.f, 0.f, 0.f};

    for (int q = 0; q < 8; ++q) {
        // (a) prefetch weight tile: 3 x dwordx4 / thread (96 rows x 8 slots)
        uint4 wreg[3];
#pragma unroll
        for (int r = 0; r < 3; ++r) {
            int u = tid + 256 * r;
            int n = u >> 3, sl = u & 7;
            int n_glob = (n >> 5) * 256 + ct * 32 + (n & 31);
            int koff = (sl < 4) ? (q * 32 + sl * 8) : (256 + q * 32 + (sl - 4) * 8);
            wreg[r] = *(const uint4*)(fw2t2 + (size_t)n_glob * 512 + koff);
        }
        // (b) h chunk via split MFMA (wave-private)
        f32x4 hacc[2][2];
#pragma unroll
        for (int cf = 0; cf < 2; cf++)
#pragma unroll
            for (int ef = 0; ef < 2; ef++) hacc[cf][ef] = (f32x4){0.f, 0.f, 0.f, 0.f};
#pragma unroll
        for (int cf = 0; cf < 2; ++cf) {
            const unsigned short* ar = fw1t2 + (size_t)(q * 32 + cf * 16 + l16) * 64;
            bf16x8 ahi = *(const bf16x8*)(ar + g4 * 8);
            bf16x8 alo = *(const bf16x8*)(ar + 32 + g4 * 8);
#pragma unroll
            for (int ef = 0; ef < 2; ++ef) {
                hacc[cf][ef] = MFMA16(ahi, bfr_hi[ef], hacc[cf][ef], 0, 0, 0);
                hacc[cf][ef] = MFMA16(ahi, bfr_lo[ef], hacc[cf][ef], 0, 0, 0);
                hacc[cf][ef] = MFMA16(alo, bfr_hi[ef], hacc[cf][ef], 0, 0, 0);
            }
        }
        // silu (fp32) + split + store to s_h2 (own rows only)
#pragma unroll
        for (int cf = 0; cf < 2; ++cf) {
            int cbase = cf * 16 + g4 * 4;
            float4 b1 = *(const float4*)(fb1 + q * 32 + cbase);
#pragma unroll
            for (int ef = 0; ef < 2; ++ef) {
                int e = 32 * w + 16 * ef + l16;
                float h0 = silu_f(hacc[cf][ef][0] + b1.x);
                float h1 = silu_f(hacc[cf][ef][1] + b1.y);
                float h2 = silu_f(hacc[cf][ef][2] + b1.z);
                float h3 = silu_f(hacc[cf][ef][3] + b1.w);
                unsigned i0 = f2bf(h0), i1 = f2bf(h1), i2 = f2bf(h2), i3 = f2bf(h3);
                unsigned o0 = f2bf(h0 - bf2f((unsigned short)i0));
                unsigned o1 = f2bf(h1 - bf2f((unsigned short)i1));
                unsigned o2 = f2bf(h2 - bf2f((unsigned short)i2));
                unsigned o3 = f2bf(h3 - bf2f((unsigned short)i3));
                uint2 phi, plo;
                phi.x = i0 | (i1 << 16); phi.y = i2 | (i3 << 16);
                plo.x = o0 | (o1 << 16); plo.y = o2 | (o3 << 16);
                char* base = s_h2 + e * 128;
                int swz = (e & 7) << 4;
                *(uint2*)(base + ((2 * cbase) ^ swz)) = phi;
                *(uint2*)(base + ((64 + 2 * cbase) ^ swz)) = plo;
            }
        }
        // (c) write weight tile to LDS (WAR barrier first)
        __syncthreads();
#pragma unroll
        for (int r = 0; r < 3; ++r) {
            int u = tid + 256 * r;
            int n = u >> 3, sl = u & 7;
            *(uint4*)(s_w2 + n * 128 + ((sl * 16) ^ ((n & 7) << 4))) = wreg[r];
        }
        __syncthreads();
        // (d) main MFMA: 3 split combos, 6 n-frags x 2 e-frags
        bf16x8 bh_hi[2], bh_lo[2];
#pragma unroll
        for (int ef = 0; ef < 2; ef++) {
            int e = 32 * w + 16 * ef + l16;
            int swz = (e & 7) << 4;
            bh_hi[ef] = *(const bf16x8*)(s_h2 + e * 128 + ((16 * g4) ^ swz));
            bh_lo[ef] = *(const bf16x8*)(s_h2 + e * 128 + ((64 + 16 * g4) ^ swz));
        }
#pragma unroll
        for (int nf = 0; nf < 6; nf++) {
            int n = nf * 16 + l16;
            int swzn = (n & 7) << 4;
            bf16x8 aw_hi = *(const bf16x8*)(s_w2 + n * 128 + ((16 * g4) ^ swzn));
            bf16x8 aw_lo = *(const bf16x8*)(s_w2 + n * 128 + ((64 + 16 * g4) ^ swzn));
#pragma unroll
            for (int ef = 0; ef < 2; ef++) {
                acc[nf][ef] = MFMA16(aw_hi, bh_hi[ef], acc[nf][ef], 0, 0, 0);
                acc[nf][ef] = MFMA16(aw_hi, bh_lo[ef], acc[nf][ef], 0, 0, 0);
                acc[nf][ef] = MFMA16(aw_lo, bh_hi[ef], acc[nf][ef], 0, 0, 0);
            }
        }
    }

    // ---------------- epilogue ----------------
#pragma unroll
    for (int ef = 0; ef < 2; ++ef) {
        int E = e0 + 32 * w + 16 * ef + l16;
        int ai = si[E], aj = sj[E];
        float fc = sfc[E];
        float d0 = sdir[3 * E], d1 = sdir[3 * E + 1], d2 = sdir[3 * E + 2];
        int i1 = __shfl_down(ai, 1, 16), i2 = __shfl_down(ai, 2, 16);
        int i4 = __shfl_down(ai, 4, 16), i8 = __shfl_down(ai, 8, 16);
        int prevai = __shfl_up(ai, 1, 16);
        bool m1 = (l16 + 1 < 16) && (i1 == ai);
        bool m2 = (l16 + 2 < 16) && (i2 == ai);
        bool m4 = (l16 + 4 < 16) && (i4 == ai);
        bool m8 = (l16 + 8 < 16) && (i8 == ai);
        bool lead = (l16 == 0) || (prevai != ai);
        const float* cj = ctx + (size_t)aj * H3;
        const float* vj = v_in + (size_t)aj * H3;
#pragma unroll
        for (int ci = 0; ci < 2; ++ci) {
            int Cb = ct * 32 + ci * 16 + g4 * 4;
            float4 c0 = *(const float4*)(cj + Cb);
            float4 c1 = *(const float4*)(cj + H + Cb);
            float4 c2 = *(const float4*)(cj + 2 * H + Cb);
            float4 u0 = *(const float4*)(vj + Cb);
            float4 u1 = *(const float4*)(vj + H + Cb);
            float4 u2 = *(const float4*)(vj + 2 * H + Cb);
            float4 b0 = *(const float4*)(fb2 + Cb);
            float4 b1 = *(const float4*)(fb2 + H + Cb);
            float4 b2 = *(const float4*)(fb2 + 2 * H + Cb);
            float vds[4], vv0[4], vv1[4], vv2[4];
#pragma unroll
            for (int r = 0; r < 4; ++r) {
                float w0 = acc[ci][ef][r]     + ((const float*)&b0)[r];
                float w1 = acc[2 + ci][ef][r] + ((const float*)&b1)[r];
                float w2 = acc[4 + ci][ef][r] + ((const float*)&b2)[r];
                float ds  = ((const float*)&c0)[r] * w0 * fc;
                float dvs = ((const float*)&c1)[r] * w1 * fc;
                float dvv = ((const float*)&c2)[r] * w2 * fc;
                vds[r] = ds;
                vv0[r] = dvs * d0 + dvv * ((const float*)&u0)[r];
                vv1[r] = dvs * d1 + dvv * ((const float*)&u1)[r];
                vv2[r] = dvs * d2 + dvv * ((const float*)&u2)[r];
            }
#pragma unroll
            for (int st = 0; st < 4; ++st) {
                int off = 1 << st;
                bool m = (st == 0) ? m1 : (st == 1) ? m2 : (st == 2) ? m4 : m8;
#pragma unroll
                for (int r = 0; r < 4; ++r) {
                    float t0 = __shfl_down(vds[r], off, 16);
                    float t1 = __shfl_down(vv0[r], off, 16);
                    float t2 = __shfl_down(vv1[r], off, 16);
                    float t3 = __shfl_down(vv2[r], off, 16);
                    if (m) { vds[r] += t0; vv0[r] += t1; vv1[r] += t2; vv2[r] += t3; }
                }
            }
            if (lead) {
#pragma unroll
                for (int r = 0; r < 4; ++r) {
                    int C = Cb + r;
                    atomicAdd(&out_s[(size_t)ai * H + C], vds[r]);
                    atomicAdd(&out_v[(size_t)ai * H3 + C], vv0[r]);
                    atomicAdd(&out_v[(size_t)ai * H3 + H + C], vv1[r]);
                    atomicAdd(&out_v[(size_t)ai * H3 + 2 * H + C], vv2[r]);
                }
            }
        }
    }
}

extern "C" void kernel_launch(void* const* d_in, const int* in_sizes, int n_in,
                              void* d_out, int out_size, void* d_ws, size_t ws_size,
                              hipStream_t stream) {
    const float* s      = (const float*)d_in[0];
    const float* v      = (const float*)d_in[1];
    const int*   idx_i  = (const int*)d_in[2];
    const int*   idx_j  = (const int*)d_in[3];
    const float* rbf    = (const float*)d_in[4];
    const float* f_cut  = (const float*)d_in[5];
    const float* dir_ij = (const float*)d_in[6];
    const float* inv    = (const float*)d_in[7];
    const float* ln_g   = (const float*)d_in[8];
    const float* ln_b   = (const float*)d_in[9];
    const float* cw1    = (const float*)d_in[10];
    const float* cb1    = (const float*)d_in[11];
    const float* cw2    = (const float*)d_in[12];
    const float* cb2    = (const float*)d_in[13];
    const float* fw1    = (const float*)d_in[14];
    const float* fb1    = (const float*)d_in[15];
    const float* fw2    = (const float*)d_in[16];
    const float* fb2    = (const float*)d_in[17];

    float* out_s = (float*)d_out;
    float* out_v = out_s + (size_t)N_ATOMS * H;

    // ---- ws layout (bytes), peak 47,022,080 (< 51.2MB proven) ----
    char* wsb = (char*)d_ws;
    unsigned short* fw2t2    = (unsigned short*)(wsb + 0);          //    786,432
    unsigned short* fw1t2    = (unsigned short*)(wsb + 786432);     //     32,768
    int*            counts   = (int*)(wsb + 819200);                //     40,960
    int*            rowstart = (int*)(wsb + 860160);                //     40,960
    int*            cursor   = (int*)(wsb + 901120);                //     40,960
    float*          ctx      = (float*)(wsb + 942080);              // 30,720,000 fp32
    float*          sn       = (float*)(wsb + 31662080);            // 10,240,000
    unsigned short* ctx1     = (unsigned short*)(wsb + 41902080);   //  5,120,000 bf16
    // overlays of sn region (written only after gemm1 consumed sn):
    int*            perm     = (int*)(wsb + 31662080);              //  1,280,000
    int*            si       = (int*)(wsb + 32942080);
    int*            sj       = (int*)(wsb + 34222080);
    float*          sfc      = (float*)(wsb + 35502080);
    float*          sdir     = (float*)(wsb + 36782080);            //  3,840,000

    // init outputs with s, v (updates accumulated atomically on top)
    hipMemcpyAsync(out_s, s, sizeof(float) * (size_t)N_ATOMS * H,
                   hipMemcpyDeviceToDevice, stream);
    hipMemcpyAsync(out_v, v, sizeof(float) * (size_t)N_ATOMS * 3 * H,
                   hipMemcpyDeviceToDevice, stream);
    hipMemsetAsync(counts, 0, 122880, stream);   // counts+rowstart+cursor

    // weight prep + histogram
    k_prep_fw2t2<<<768, 256, 0, stream>>>(fw2, fw2t2);
    k_prep_fw1t2<<<1, 256, 0, stream>>>(fw1, fw1t2);
    k_hist<<<(N_EDGES + 255) / 256, 256, 0, stream>>>(idx_i, counts);
    k_scan<<<1, 256, 0, stream>>>(counts, rowstart);

    // context path (uses sn, then ctx1, then ctx)
    k_ln<<<N_ATOMS, 256, 0, stream>>>(s, ln_g, ln_b, sn);
    dim3 g1((N_ATOMS + 63) / 64, H / 64);
    k_gemm<1, 0, 1><<<g1, 256, 0, stream>>>(sn, cw1, cb1, ctx1, N_ATOMS, H, H);

    // sort outputs overlay sn (dead now)
    k_scatter<<<(N_EDGES + 255) / 256, 256, 0, stream>>>(idx_i, rowstart, cursor, perm);
    k_gather<<<(N_EDGES + 255) / 256, 256, 0, stream>>>(
        perm, idx_i, idx_j, f_cut, dir_ij, inv, si, sj, sfc, sdir);

    dim3 g2((N_ATOMS + 63) / 64, H3 / 64);
    k_gemm<0, 1, 0><<<g2, 256, 0, stream>>>(ctx1, cw2, cb2, ctx, N_ATOMS, H3, H);

    // fused edge GEMM + scatter
    dim3 ge(N_EDGES / 128, 8);
    k_edge<<<ge, 256, 0, stream>>>(perm, rbf, si, sj, sfc, sdir, fw1t2, fb1,
                                   fw2t2, fb2, ctx, v, out_s, out_v);
}